// Round 1
// baseline (246.771 us; speedup 1.0000x reference)
//
#include <hip/hip_runtime.h>

// ---------------------------------------------------------------------------
// Problem constants
//   x: (32, 512, 128) fp32 -> rows r = b*128 + c, 4096 rows
//   h[r][n2] = sum_l xt[r][l] * W2[n2][l] + b2[n2],  W2 = lin2_w @ lin1_w
//   out[r][t] = h[r][t] + mamba1(h[r][:])[t]        (x1 branch is exactly 0)
// ---------------------------------------------------------------------------

__device__ __forceinline__ float silu_f(float x) {
    return x / (1.0f + __expf(-x));
}
__device__ __forceinline__ float softplus_f(float x) {
    // stable: max(x,0) + log1p(exp(-|x|))
    return fmaxf(x, 0.0f) + log1pf(__expf(-fabsf(x)));
}

// ---------------------------------------------------------------------------
// Kernel 1: W2T[l*256 + n2] = sum_n1 lin2_w[n2][n1] * lin1_w[n1][l]
// GEMM M=256(n2) N=512(l) K=512. BM=32 BN=32 BK=64, grid(8,16), 256 thr, 2x2 micro.
// ---------------------------------------------------------------------------
__global__ __launch_bounds__(256)
void gemm_w2t(const float* __restrict__ A,   // lin2_w (256,512) row-major [m][k]
              const float* __restrict__ B,   // lin1_w (512,512) row-major [k][n]
              float* __restrict__ W2T) {
    __shared__ float As[64][34];  // [k][m], pad keeps b64 reads aligned
    __shared__ float Bs[64][36];  // [k][n], pad keeps f4 stores aligned
    const int tid = threadIdx.x;
    const int m0 = blockIdx.x * 32;
    const int n0 = blockIdx.y * 32;
    const int tr = tid & 15;   // m pair -> m = 2*tr
    const int tc = tid >> 4;   // n pair -> n = 2*tc
    const int ma  = tid >> 3;  // 0..31  A-staging m
    const int kqa = tid & 7;   // A-staging k-octet
    const int kb  = tid >> 2;  // 0..63  B-staging k
    const int nqb = tid & 3;   // B-staging n-octet
    float acc00 = 0.f, acc01 = 0.f, acc10 = 0.f, acc11 = 0.f;

    for (int k0 = 0; k0 < 512; k0 += 64) {
        float4 a0 = *(const float4*)&A[(m0 + ma) * 512 + k0 + kqa * 8];
        float4 a1 = *(const float4*)&A[(m0 + ma) * 512 + k0 + kqa * 8 + 4];
        As[kqa * 8 + 0][ma] = a0.x;
        As[kqa * 8 + 1][ma] = a0.y;
        As[kqa * 8 + 2][ma] = a0.z;
        As[kqa * 8 + 3][ma] = a0.w;
        As[kqa * 8 + 4][ma] = a1.x;
        As[kqa * 8 + 5][ma] = a1.y;
        As[kqa * 8 + 6][ma] = a1.z;
        As[kqa * 8 + 7][ma] = a1.w;
        float4 b0 = *(const float4*)&B[(k0 + kb) * 512 + n0 + nqb * 8];
        float4 b1 = *(const float4*)&B[(k0 + kb) * 512 + n0 + nqb * 8 + 4];
        *(float4*)&Bs[kb][nqb * 8]     = b0;
        *(float4*)&Bs[kb][nqb * 8 + 4] = b1;
        __syncthreads();
#pragma unroll 16
        for (int kk = 0; kk < 64; ++kk) {
            float2 av = *(const float2*)&As[kk][tr * 2];
            float2 bv = *(const float2*)&Bs[kk][tc * 2];
            acc00 = fmaf(av.x, bv.x, acc00);
            acc01 = fmaf(av.x, bv.y, acc01);
            acc10 = fmaf(av.y, bv.x, acc10);
            acc11 = fmaf(av.y, bv.y, acc11);
        }
        __syncthreads();
    }
    const int m = m0 + tr * 2;
    const int nn = n0 + tc * 2;
    W2T[nn * 256 + m]           = acc00;
    W2T[nn * 256 + m + 1]       = acc10;
    W2T[(nn + 1) * 256 + m]     = acc01;
    W2T[(nn + 1) * 256 + m + 1] = acc11;
}

// ---------------------------------------------------------------------------
// Kernel 2: b2[n2] = sum_n1 lin2_w[n2][n1]*lin1_b[n1] + lin2_b[n2]
// ---------------------------------------------------------------------------
__global__ __launch_bounds__(256)
void bias_b2(const float* __restrict__ lin2_w, const float* __restrict__ lin1_b,
             const float* __restrict__ lin2_b, float* __restrict__ b2) {
    const int tid = threadIdx.x;
    float acc = 0.f;
#pragma unroll 8
    for (int k = 0; k < 512; k += 4) {
        float4 w  = *(const float4*)&lin2_w[tid * 512 + k];
        float4 bb = *(const float4*)&lin1_b[k];
        acc += w.x * bb.x + w.y * bb.y + w.z * bb.z + w.w * bb.w;
    }
    b2[tid] = acc + lin2_b[tid];
}

// ---------------------------------------------------------------------------
// Kernel 3: h[r][n2] = sum_l xt[r][l]*W2T[l*256+n2] + b2[n2]
// xt[r][l] = x[(r>>7)*65536 + l*128 + (r&127)]
// GEMM M=4096(r) N=256(n2) K=512(l). BM=64 BN=64 BK=32, grid(64,4), 4x4 micro.
// ---------------------------------------------------------------------------
__global__ __launch_bounds__(256)
void gemm_h(const float* __restrict__ x, const float* __restrict__ W2T,
            const float* __restrict__ b2, float* __restrict__ hout) {
    __shared__ float As[32][68];  // [k][r']
    __shared__ float Bs[32][68];  // [k][n']
    const int tid = threadIdx.x;
    const int bx = blockIdx.x;       // r tile of 64
    const int n0 = blockIdx.y * 64;  // n2 tile
    const int b  = bx >> 1;
    const int c0 = (bx & 1) * 64;
    const int r0 = bx * 64;
    const int c4 = tid & 15;  // float4 column within 64
    const int ks = tid >> 4;  // 0..15, k row (2 passes)
    const int tr = tid & 15;  // r quad
    const int tc = tid >> 4;  // n quad
    float acc[4][4] = {{0.f}};

    const float* xbase = x + b * 65536 + c0 + c4 * 4;
    const float* wbase = W2T + n0 + c4 * 4;

    for (int l0 = 0; l0 < 512; l0 += 32) {
        float4 xa0 = *(const float4*)&xbase[(l0 + ks) * 128];
        float4 xa1 = *(const float4*)&xbase[(l0 + ks + 16) * 128];
        float4 wb0 = *(const float4*)&wbase[(l0 + ks) * 256];
        float4 wb1 = *(const float4*)&wbase[(l0 + ks + 16) * 256];
        *(float4*)&As[ks][c4 * 4]      = xa0;
        *(float4*)&As[ks + 16][c4 * 4] = xa1;
        *(float4*)&Bs[ks][c4 * 4]      = wb0;
        *(float4*)&Bs[ks + 16][c4 * 4] = wb1;
        __syncthreads();
#pragma unroll 8
        for (int kk = 0; kk < 32; ++kk) {
            float4 av = *(const float4*)&As[kk][tr * 4];
            float4 bv = *(const float4*)&Bs[kk][tc * 4];
            acc[0][0] = fmaf(av.x, bv.x, acc[0][0]);
            acc[0][1] = fmaf(av.x, bv.y, acc[0][1]);
            acc[0][2] = fmaf(av.x, bv.z, acc[0][2]);
            acc[0][3] = fmaf(av.x, bv.w, acc[0][3]);
            acc[1][0] = fmaf(av.y, bv.x, acc[1][0]);
            acc[1][1] = fmaf(av.y, bv.y, acc[1][1]);
            acc[1][2] = fmaf(av.y, bv.z, acc[1][2]);
            acc[1][3] = fmaf(av.y, bv.w, acc[1][3]);
            acc[2][0] = fmaf(av.z, bv.x, acc[2][0]);
            acc[2][1] = fmaf(av.z, bv.y, acc[2][1]);
            acc[2][2] = fmaf(av.z, bv.z, acc[2][2]);
            acc[2][3] = fmaf(av.z, bv.w, acc[2][3]);
            acc[3][0] = fmaf(av.w, bv.x, acc[3][0]);
            acc[3][1] = fmaf(av.w, bv.y, acc[3][1]);
            acc[3][2] = fmaf(av.w, bv.z, acc[3][2]);
            acc[3][3] = fmaf(av.w, bv.w, acc[3][3]);
        }
        __syncthreads();
    }
    const float4 bias = *(const float4*)&b2[n0 + tc * 4];
#pragma unroll
    for (int i = 0; i < 4; ++i) {
        float4 v = make_float4(acc[i][0] + bias.x, acc[i][1] + bias.y,
                               acc[i][2] + bias.z, acc[i][3] + bias.w);
        *(float4*)&hout[(r0 + tr * 4 + i) * 256 + n0 + tc * 4] = v;
    }
}

// ---------------------------------------------------------------------------
// Kernel 4: mamba1 over each row of h (sequence length 256, d_model=1,
// di=2, dt_rank=1, N=16) + residual h.  4 rows per 128-thread block,
// 32 lanes per row: lane = (d<<4)|n owns state (d,n).
// ---------------------------------------------------------------------------
__global__ __launch_bounds__(128)
void mamba_res(const float* __restrict__ h, float* __restrict__ out,
               const float* __restrict__ in_w, const float* __restrict__ conv_w,
               const float* __restrict__ conv_b, const float* __restrict__ xproj,
               const float* __restrict__ dt_w, const float* __restrict__ dt_b,
               const float* __restrict__ A_log, const float* __restrict__ Dp,
               const float* __restrict__ out_w) {
    __shared__ float4 arrA[4][256];  // {xc0, xc1, dt0, dt1}
    __shared__ float4 arrB[4][256];  // {base, w0, w1, -}
    __shared__ float  ubuf[4][256];

    const int tid = threadIdx.x;
    const int r0 = blockIdx.x * 4;

    // phase 0: stage 4 rows of h (1024 floats), coalesced
    {
        const float4* src = (const float4*)(h + r0 * 256);
        float4* dst = (float4*)&ubuf[0][0];
        dst[tid]       = src[tid];
        dst[tid + 128] = src[tid + 128];
    }

    const int row  = tid >> 5;
    const int lane = tid & 31;
    const int d    = lane >> 4;
    const int n    = lane & 15;

    // small shared parameters (L1/L2-cached broadcast loads)
    const float iw0 = in_w[0], iw1 = in_w[1], iw2 = in_w[2], iw3 = in_w[3];
    const float g00 = iw0 * conv_w[0], g01 = iw0 * conv_w[1];
    const float g02 = iw0 * conv_w[2], g03 = iw0 * conv_w[3];
    const float g10 = iw1 * conv_w[4], g11 = iw1 * conv_w[5];
    const float g12 = iw1 * conv_w[6], g13 = iw1 * conv_w[7];
    const float cb0 = conv_b[0], cb1 = conv_b[1];
    const float xp00 = xproj[0], xp01 = xproj[1];
    const float dtw0 = dt_w[0], dtw1 = dt_w[1];
    const float dtb0 = dt_b[0], dtb1 = dt_b[1];
    const float D0 = Dp[0], D1 = Dp[1];
    const float ow0 = out_w[0], ow1 = out_w[1];

    __syncthreads();

    // phase 1: per-t precompute (parallel over t; t = lane + 32*j)
#pragma unroll
    for (int j = 0; j < 8; ++j) {
        const int t = lane + 32 * j;
        const float u0 = ubuf[row][t];
        const int i1 = (t >= 1) ? t - 1 : 0;
        const int i2 = (t >= 2) ? t - 2 : 0;
        const int i3 = (t >= 3) ? t - 3 : 0;
        float um1 = ubuf[row][i1]; um1 = (t >= 1) ? um1 : 0.f;
        float um2 = ubuf[row][i2]; um2 = (t >= 2) ? um2 : 0.f;
        float um3 = ubuf[row][i3]; um3 = (t >= 3) ? um3 : 0.f;

        const float p0 = fmaf(g03, u0, fmaf(g02, um1, fmaf(g01, um2, fmaf(g00, um3, cb0))));
        const float p1 = fmaf(g13, u0, fmaf(g12, um1, fmaf(g11, um2, fmaf(g10, um3, cb1))));
        const float xc0 = silu_f(p0);
        const float xc1 = silu_f(p1);
        const float dbc0 = fmaf(xp01, xc1, xp00 * xc0);
        const float dt0 = softplus_f(fmaf(dbc0, dtw0, dtb0));
        const float dt1 = softplus_f(fmaf(dbc0, dtw1, dtb1));
        const float sz0 = silu_f(u0 * iw2);
        const float sz1 = silu_f(u0 * iw3);
        const float w0 = sz0 * ow0;
        const float w1 = sz1 * ow1;
        const float base = fmaf(xc1 * D1, w1, fmaf(xc0 * D0, w0, u0));
        arrA[row][t] = make_float4(xc0, xc1, dt0, dt1);
        arrB[row][t] = make_float4(base, w0, w1, 0.f);
    }
    __syncthreads();

    // phase 2: sequential scan, lane owns state (d, n)
    const float a_dn = -__expf(A_log[d * 16 + n]);
    const float bn0 = xproj[(1 + n) * 2 + 0];
    const float bn1 = xproj[(1 + n) * 2 + 1];
    const float cn0 = xproj[(17 + n) * 2 + 0];
    const float cn1 = xproj[(17 + n) * 2 + 1];
    float hstate = 0.f;
    float* orow = out + (r0 + row) * 256;

#pragma unroll 4
    for (int t = 0; t < 256; ++t) {
        const float4 A4 = arrA[row][t];
        const float4 B4 = arrB[row][t];
        const float dtd = d ? A4.w : A4.z;
        const float xcd = d ? A4.y : A4.x;
        const float Bm = fmaf(bn1, A4.y, bn0 * A4.x);
        const float Cm = fmaf(cn1, A4.y, cn0 * A4.x);
        const float dA = __expf(dtd * a_dn);
        hstate = fmaf(dA, hstate, dtd * xcd * Bm);
        float s = hstate * Cm;
        s += __shfl_xor(s, 1, 32);
        s += __shfl_xor(s, 2, 32);
        s += __shfl_xor(s, 4, 32);
        s += __shfl_xor(s, 8, 32);
        const float so = __shfl_xor(s, 16, 32);
        if (lane == 0) {
            // lane 0: d=0 -> s = S0, so = S1
            orow[t] = fmaf(B4.z, so, fmaf(B4.y, s, B4.x));
        }
    }
}

// ---------------------------------------------------------------------------
extern "C" void kernel_launch(void* const* d_in, const int* in_sizes, int n_in,
                              void* d_out, int out_size, void* d_ws, size_t ws_size,
                              hipStream_t stream) {
    const float* x      = (const float*)d_in[0];
    const float* lin1_w = (const float*)d_in[1];
    const float* lin1_b = (const float*)d_in[2];
    const float* lin2_w = (const float*)d_in[3];
    const float* lin2_b = (const float*)d_in[4];
    const float* m1_in_w   = (const float*)d_in[5];
    const float* m1_conv_w = (const float*)d_in[6];
    const float* m1_conv_b = (const float*)d_in[7];
    const float* m1_xproj  = (const float*)d_in[8];
    const float* m1_dt_w   = (const float*)d_in[9];
    const float* m1_dt_b   = (const float*)d_in[10];
    const float* m1_A_log  = (const float*)d_in[11];
    const float* m1_D      = (const float*)d_in[12];
    const float* m1_out_w  = (const float*)d_in[13];
    // d_in[14..22] = m2_* params: the x1 branch is exactly zero (see analysis)

    float* out  = (float*)d_out;
    float* wsf  = (float*)d_ws;
    float* hbuf = wsf;                   // 4096*256 floats
    float* W2T  = wsf + 4096 * 256;      // 512*256 floats
    float* b2   = W2T + 512 * 256;       // 256 floats

    gemm_w2t<<<dim3(8, 16), 256, 0, stream>>>(lin2_w, lin1_w, W2T);
    bias_b2<<<1, 256, 0, stream>>>(lin2_w, lin1_b, lin2_b, b2);
    gemm_h<<<dim3(64, 4), 256, 0, stream>>>(x, W2T, b2, hbuf);
    mamba_res<<<1024, 128, 0, stream>>>(hbuf, out, m1_in_w, m1_conv_w, m1_conv_b,
                                        m1_xproj, m1_dt_w, m1_dt_b, m1_A_log,
                                        m1_D, m1_out_w);
}

// Round 2
// 197.575 us; speedup vs baseline: 1.2490x; 1.2490x over previous
//
#include <hip/hip_runtime.h>

// ---------------------------------------------------------------------------
//   x: (32, 512, 128) fp32 -> rows r = b*128 + c, 4096 rows
//   h[r][n2] = sum_l xt[r][l] * W2[n2][l] + b2[n2],  W2 = lin2_w @ lin1_w
//   out[r][t] = h[r][t] + mamba1(h[r][:])[t]        (x1 branch is exactly 0)
// ---------------------------------------------------------------------------

__device__ __forceinline__ float silu_f(float x) {
    return x / (1.0f + __expf(-x));
}
__device__ __forceinline__ float softplus_f(float x) {
    return fmaxf(x, 0.0f) + log1pf(__expf(-fabsf(x)));
}

// DPP row_shr add (rows of 16 lanes); bound_ctrl=1 -> out-of-row reads 0.
#define DPP_ADD(s, ctrl)                                                       \
    (s) += __int_as_float(__builtin_amdgcn_update_dpp(                         \
        0, __float_as_int(s), (ctrl), 0xf, 0xf, true))

// ---------------------------------------------------------------------------
// Kernel 1: W2T[l*256 + n2] = sum_n1 lin2_w[n2][n1] * lin1_w[n1][l]
// ---------------------------------------------------------------------------
__global__ __launch_bounds__(256)
void gemm_w2t(const float* __restrict__ A,   // lin2_w (256,512) [m][k]
              const float* __restrict__ B,   // lin1_w (512,512) [k][n]
              float* __restrict__ W2T) {
    __shared__ float As[64][34];
    __shared__ float Bs[64][36];
    const int tid = threadIdx.x;
    const int m0 = blockIdx.x * 32;
    const int n0 = blockIdx.y * 32;
    const int tr = tid & 15;
    const int tc = tid >> 4;
    const int ma  = tid >> 3;
    const int kqa = tid & 7;
    const int kb  = tid >> 2;
    const int nqb = tid & 3;
    float acc00 = 0.f, acc01 = 0.f, acc10 = 0.f, acc11 = 0.f;

    for (int k0 = 0; k0 < 512; k0 += 64) {
        float4 a0 = *(const float4*)&A[(m0 + ma) * 512 + k0 + kqa * 8];
        float4 a1 = *(const float4*)&A[(m0 + ma) * 512 + k0 + kqa * 8 + 4];
        As[kqa * 8 + 0][ma] = a0.x;
        As[kqa * 8 + 1][ma] = a0.y;
        As[kqa * 8 + 2][ma] = a0.z;
        As[kqa * 8 + 3][ma] = a0.w;
        As[kqa * 8 + 4][ma] = a1.x;
        As[kqa * 8 + 5][ma] = a1.y;
        As[kqa * 8 + 6][ma] = a1.z;
        As[kqa * 8 + 7][ma] = a1.w;
        float4 b0 = *(const float4*)&B[(k0 + kb) * 512 + n0 + nqb * 8];
        float4 b1 = *(const float4*)&B[(k0 + kb) * 512 + n0 + nqb * 8 + 4];
        *(float4*)&Bs[kb][nqb * 8]     = b0;
        *(float4*)&Bs[kb][nqb * 8 + 4] = b1;
        __syncthreads();
#pragma unroll 16
        for (int kk = 0; kk < 64; ++kk) {
            float2 av = *(const float2*)&As[kk][tr * 2];
            float2 bv = *(const float2*)&Bs[kk][tc * 2];
            acc00 = fmaf(av.x, bv.x, acc00);
            acc01 = fmaf(av.x, bv.y, acc01);
            acc10 = fmaf(av.y, bv.x, acc10);
            acc11 = fmaf(av.y, bv.y, acc11);
        }
        __syncthreads();
    }
    const int m = m0 + tr * 2;
    const int nn = n0 + tc * 2;
    W2T[nn * 256 + m]           = acc00;
    W2T[nn * 256 + m + 1]       = acc10;
    W2T[(nn + 1) * 256 + m]     = acc01;
    W2T[(nn + 1) * 256 + m + 1] = acc11;
}

// ---------------------------------------------------------------------------
// Kernel 2: b2[n2] = sum_n1 lin2_w[n2][n1]*lin1_b[n1] + lin2_b[n2]
// 8 blocks x 256 thr: 32 n per block, 8-way k-split + LDS reduce.
// ---------------------------------------------------------------------------
__global__ __launch_bounds__(256)
void bias_b2(const float* __restrict__ lin2_w, const float* __restrict__ lin1_b,
             const float* __restrict__ lin2_b, float* __restrict__ b2) {
    __shared__ float red[8][33];
    const int tid = threadIdx.x;
    const int np = tid & 31;
    const int ks = tid >> 5;
    const int n = blockIdx.x * 32 + np;
    float acc = 0.f;
#pragma unroll 16
    for (int k = ks * 64; k < ks * 64 + 64; k += 4) {
        float4 w  = *(const float4*)&lin2_w[n * 512 + k];
        float4 bb = *(const float4*)&lin1_b[k];
        acc += w.x * bb.x + w.y * bb.y + w.z * bb.z + w.w * bb.w;
    }
    red[ks][np] = acc;
    __syncthreads();
    if (ks == 0) {
        float s = red[0][np] + red[1][np] + red[2][np] + red[3][np] +
                  red[4][np] + red[5][np] + red[6][np] + red[7][np];
        b2[n] = s + lin2_b[n];
    }
}

// ---------------------------------------------------------------------------
// Kernel 3: h[r][n2] = sum_l xt[r][l]*W2T[l*256+n2] + b2[n2]   (LDS-free)
// xt[r][l] = x[(r>>7)*65536 + l*128 + (r&127)]
// Both fragments are contiguous in global memory:
//   A: x[b][l][c0+4tr .. +3]   (16 distinct float4/wave, broadcast x4)
//   B: W2T[l][n0+4tc .. +3]    (4 distinct float4/wave, broadcast x16)
// ---------------------------------------------------------------------------
__global__ __launch_bounds__(256)
void gemm_h(const float* __restrict__ x, const float* __restrict__ W2T,
            const float* __restrict__ b2, float* __restrict__ hout) {
    const int tid = threadIdx.x;
    const int bx = blockIdx.x;       // r tile of 64
    const int n0 = blockIdx.y * 64;  // n2 tile
    const int b  = bx >> 1;
    const int c0 = (bx & 1) * 64;
    const int r0 = bx * 64;
    const int tr = tid & 15;   // r quad
    const int tc = tid >> 4;   // n quad
    float acc[4][4] = {{0.f}};

    const float* xp = x + b * 65536 + c0 + tr * 4;
    const float* wp = W2T + n0 + tc * 4;

#pragma unroll 8
    for (int l = 0; l < 512; ++l) {
        float4 av = *(const float4*)&xp[l * 128];
        float4 bv = *(const float4*)&wp[l * 256];
        acc[0][0] = fmaf(av.x, bv.x, acc[0][0]);
        acc[0][1] = fmaf(av.x, bv.y, acc[0][1]);
        acc[0][2] = fmaf(av.x, bv.z, acc[0][2]);
        acc[0][3] = fmaf(av.x, bv.w, acc[0][3]);
        acc[1][0] = fmaf(av.y, bv.x, acc[1][0]);
        acc[1][1] = fmaf(av.y, bv.y, acc[1][1]);
        acc[1][2] = fmaf(av.y, bv.z, acc[1][2]);
        acc[1][3] = fmaf(av.y, bv.w, acc[1][3]);
        acc[2][0] = fmaf(av.z, bv.x, acc[2][0]);
        acc[2][1] = fmaf(av.z, bv.y, acc[2][1]);
        acc[2][2] = fmaf(av.z, bv.z, acc[2][2]);
        acc[2][3] = fmaf(av.z, bv.w, acc[2][3]);
        acc[3][0] = fmaf(av.w, bv.x, acc[3][0]);
        acc[3][1] = fmaf(av.w, bv.y, acc[3][1]);
        acc[3][2] = fmaf(av.w, bv.z, acc[3][2]);
        acc[3][3] = fmaf(av.w, bv.w, acc[3][3]);
    }
    const float4 bias = *(const float4*)&b2[n0 + tc * 4];
#pragma unroll
    for (int i = 0; i < 4; ++i) {
        float4 v = make_float4(acc[i][0] + bias.x, acc[i][1] + bias.y,
                               acc[i][2] + bias.z, acc[i][3] + bias.w);
        *(float4*)&hout[(r0 + tr * 4 + i) * 256 + n0 + tc * 4] = v;
    }
}

// ---------------------------------------------------------------------------
// Kernel 4: mamba1 over each row of h (L=256, di=2, dt_rank=1, N=16) + h.
// 4 rows per 128-thread block; 32 lanes per row: lane = (d<<4)|n.
// Phase 1 (t-parallel): conv->silu->xc, dt, e=dt*xc, w0/w1/base.
//   arrS[row][t][d] = {xc0, xc1, dt_d, e_d}   (one b128/t in scan; d-halves
//   read 2 broadcast addresses -> conflict-free; rows 2-way = free)
// Phase 2 (scan): per t: 1 ds_read_b128 + ~12 VALU + 4-stage DPP row_shr
//   reduce (lanes 0-15 = d0, 16-31 = d1 -> S_d lands in lanes 15/31).
// Phase 3 (t-parallel): y = base + w0*S0 + w1*S1, coalesced store.
// ---------------------------------------------------------------------------
__global__ __launch_bounds__(128)
void mamba_res(const float* __restrict__ h, float* __restrict__ out,
               const float* __restrict__ in_w, const float* __restrict__ conv_w,
               const float* __restrict__ conv_b, const float* __restrict__ xproj,
               const float* __restrict__ dt_w, const float* __restrict__ dt_b,
               const float* __restrict__ A_log, const float* __restrict__ Dp,
               const float* __restrict__ out_w) {
    __shared__ float4 arrS4[4 * 256 * 2];  // 32 KB
    __shared__ float  smem2[2048];         // 8 KB: ubuf (ph0/1) then Sbuf (ph2/3)

    const int tid = threadIdx.x;
    const int r0 = blockIdx.x * 4;
    const int row  = tid >> 5;
    const int lane = tid & 31;
    const int d    = lane >> 4;
    const int n    = lane & 15;

    // phase 0: stage 4 rows of h (coalesced) into smem2[0..1023]
    {
        const float4* src = (const float4*)(h + r0 * 256);
        float4* dst = (float4*)&smem2[0];
        dst[tid]       = src[tid];
        dst[tid + 128] = src[tid + 128];
    }

    const float iw0 = in_w[0], iw1 = in_w[1], iw2 = in_w[2], iw3 = in_w[3];
    const float g00 = iw0 * conv_w[0], g01 = iw0 * conv_w[1];
    const float g02 = iw0 * conv_w[2], g03 = iw0 * conv_w[3];
    const float g10 = iw1 * conv_w[4], g11 = iw1 * conv_w[5];
    const float g12 = iw1 * conv_w[6], g13 = iw1 * conv_w[7];
    const float cb0 = conv_b[0], cb1 = conv_b[1];
    const float xp00 = xproj[0], xp01 = xproj[1];
    const float dtw0 = dt_w[0], dtw1 = dt_w[1];
    const float dtb0 = dt_b[0], dtb1 = dt_b[1];
    const float D0 = Dp[0], D1 = Dp[1];
    const float ow0 = out_w[0], ow1 = out_w[1];

    __syncthreads();

    // phase 1: per-t precompute; keep w0/w1/base in registers for phase 3
    float w0a[8], w1a[8], basea[8];
#pragma unroll
    for (int j = 0; j < 8; ++j) {
        const int t = lane + 32 * j;
        const float* u = &smem2[row * 256];
        const float u0 = u[t];
        const int i1 = (t >= 1) ? t - 1 : 0;
        const int i2 = (t >= 2) ? t - 2 : 0;
        const int i3 = (t >= 3) ? t - 3 : 0;
        float um1 = u[i1]; um1 = (t >= 1) ? um1 : 0.f;
        float um2 = u[i2]; um2 = (t >= 2) ? um2 : 0.f;
        float um3 = u[i3]; um3 = (t >= 3) ? um3 : 0.f;

        const float p0 = fmaf(g03, u0, fmaf(g02, um1, fmaf(g01, um2, fmaf(g00, um3, cb0))));
        const float p1 = fmaf(g13, u0, fmaf(g12, um1, fmaf(g11, um2, fmaf(g10, um3, cb1))));
        const float xc0 = silu_f(p0);
        const float xc1 = silu_f(p1);
        const float dbc0 = fmaf(xp01, xc1, xp00 * xc0);
        const float dt0 = softplus_f(fmaf(dbc0, dtw0, dtb0));
        const float dt1 = softplus_f(fmaf(dbc0, dtw1, dtb1));
        const float e0 = dt0 * xc0;
        const float e1 = dt1 * xc1;
        const float w0 = silu_f(u0 * iw2) * ow0;
        const float w1 = silu_f(u0 * iw3) * ow1;
        w0a[j] = w0;
        w1a[j] = w1;
        basea[j] = fmaf(xc1 * D1, w1, fmaf(xc0 * D0, w0, u0));
        const int base_idx = (row * 256 + t) * 2;
        arrS4[base_idx]     = make_float4(xc0, xc1, dt0, e0);
        arrS4[base_idx + 1] = make_float4(xc0, xc1, dt1, e1);
    }
    __syncthreads();  // arrS ready; smem2 (ubuf) free to be reused as Sbuf

    // phase 2: sequential scan; lane owns state (d, n)
    const float a_dn = -__expf(A_log[d * 16 + n]);
    const float bn0 = xproj[(1 + n) * 2 + 0];
    const float bn1 = xproj[(1 + n) * 2 + 1];
    const float cn0 = xproj[(17 + n) * 2 + 0];
    const float cn1 = xproj[(17 + n) * 2 + 1];
    const bool is_writer = ((lane & 15) == 15);
    float hstate = 0.f;

#pragma unroll 4
    for (int t = 0; t < 256; ++t) {
        const float4 P = arrS4[((row * 256 + t) << 1) + d];  // {xc0,xc1,dt_d,e_d}
        const float bm = fmaf(bn0, P.x, bn1 * P.y);
        const float cm = fmaf(cn0, P.x, cn1 * P.y);
        const float dA = __expf(P.z * a_dn);
        hstate = fmaf(dA, hstate, P.w * bm);
        float s = hstate * cm;
        DPP_ADD(s, 0x111);  // row_shr:1
        DPP_ADD(s, 0x112);  // row_shr:2
        DPP_ADD(s, 0x114);  // row_shr:4
        DPP_ADD(s, 0x118);  // row_shr:8 -> lane15 of each 16-row has S_d
        if (is_writer) smem2[((row * 256 + t) << 1) + d] = s;
    }
    __syncthreads();

    // phase 3: y = base + w0*S0 + w1*S1, coalesced stores
    float* orow = out + (r0 + row) * 256;
#pragma unroll
    for (int j = 0; j < 8; ++j) {
        const int t = lane + 32 * j;
        const float2 S = *(const float2*)&smem2[((row * 256 + t) << 1)];
        orow[t] = fmaf(w1a[j], S.y, fmaf(w0a[j], S.x, basea[j]));
    }
}

// ---------------------------------------------------------------------------
extern "C" void kernel_launch(void* const* d_in, const int* in_sizes, int n_in,
                              void* d_out, int out_size, void* d_ws, size_t ws_size,
                              hipStream_t stream) {
    const float* x      = (const float*)d_in[0];
    const float* lin1_w = (const float*)d_in[1];
    const float* lin1_b = (const float*)d_in[2];
    const float* lin2_w = (const float*)d_in[3];
    const float* lin2_b = (const float*)d_in[4];
    const float* m1_in_w   = (const float*)d_in[5];
    const float* m1_conv_w = (const float*)d_in[6];
    const float* m1_conv_b = (const float*)d_in[7];
    const float* m1_xproj  = (const float*)d_in[8];
    const float* m1_dt_w   = (const float*)d_in[9];
    const float* m1_dt_b   = (const float*)d_in[10];
    const float* m1_A_log  = (const float*)d_in[11];
    const float* m1_D      = (const float*)d_in[12];
    const float* m1_out_w  = (const float*)d_in[13];
    // d_in[14..22] = m2_* params: x1 branch is exactly zero (see analysis)

    float* out  = (float*)d_out;
    float* wsf  = (float*)d_ws;
    float* hbuf = wsf;                   // 4096*256 floats
    float* W2T  = wsf + 4096 * 256;      // 512*256 floats
    float* b2   = W2T + 512 * 256;       // 256 floats

    gemm_w2t<<<dim3(8, 16), 256, 0, stream>>>(lin2_w, lin1_w, W2T);
    bias_b2<<<8, 256, 0, stream>>>(lin2_w, lin1_b, lin2_b, b2);
    gemm_h<<<dim3(64, 4), 256, 0, stream>>>(x, W2T, b2, hbuf);
    mamba_res<<<1024, 128, 0, stream>>>(hbuf, out, m1_in_w, m1_conv_w, m1_conv_b,
                                        m1_xproj, m1_dt_w, m1_dt_b, m1_A_log,
                                        m1_D, m1_out_w);
}

// Round 3
// 165.700 us; speedup vs baseline: 1.4893x; 1.1924x over previous
//
#include <hip/hip_runtime.h>

// ---------------------------------------------------------------------------
//   x: (32, 512, 128) fp32 -> rows r = b*128 + c, 4096 rows
//   h[r][n2] = sum_l xt[r][l] * W2[n2][l] + b2[n2],  W2 = lin2_w @ lin1_w
//   out[r][t] = h[r][t] + mamba1(h[r][:])[t]        (x1 branch is exactly 0)
// ---------------------------------------------------------------------------

__device__ __forceinline__ float silu_f(float x) {
    return x / (1.0f + __expf(-x));
}
__device__ __forceinline__ float softplus_f(float x) {
    return fmaxf(x, 0.0f) + log1pf(__expf(-fabsf(x)));
}

// DPP row_shr add (rows of 16 lanes); bound_ctrl=1 -> out-of-row reads 0.
#define DPP_ADD(s, ctrl)                                                       \
    (s) += __int_as_float(__builtin_amdgcn_update_dpp(                         \
        0, __float_as_int(s), (ctrl), 0xf, 0xf, true))

// ---------------------------------------------------------------------------
// Kernel 1: split-K partials of W2T[l*256+n2] = sum_n1 lin2[n2][n1]*lin1[n1][l]
// grid (8,16,4): bz = k-chunk of 128. Full-chip occupancy (512 blocks).
// ---------------------------------------------------------------------------
__global__ __launch_bounds__(256)
void gemm_w2t_part(const float* __restrict__ A,   // lin2_w (256,512) [m][k]
                   const float* __restrict__ B,   // lin1_w (512,512) [k][n]
                   float* __restrict__ parts) {
    __shared__ float As[64][34];
    __shared__ float Bs[64][36];
    const int tid = threadIdx.x;
    const int m0 = blockIdx.x * 32;
    const int n0 = blockIdx.y * 32;
    const int kbase = blockIdx.z * 128;
    const int tr = tid & 15;
    const int tc = tid >> 4;
    const int ma  = tid >> 3;
    const int kqa = tid & 7;
    const int kb  = tid >> 2;
    const int nqb = tid & 3;
    float acc00 = 0.f, acc01 = 0.f, acc10 = 0.f, acc11 = 0.f;

    for (int k0 = kbase; k0 < kbase + 128; k0 += 64) {
        float4 a0 = *(const float4*)&A[(m0 + ma) * 512 + k0 + kqa * 8];
        float4 a1 = *(const float4*)&A[(m0 + ma) * 512 + k0 + kqa * 8 + 4];
        As[kqa * 8 + 0][ma] = a0.x;
        As[kqa * 8 + 1][ma] = a0.y;
        As[kqa * 8 + 2][ma] = a0.z;
        As[kqa * 8 + 3][ma] = a0.w;
        As[kqa * 8 + 4][ma] = a1.x;
        As[kqa * 8 + 5][ma] = a1.y;
        As[kqa * 8 + 6][ma] = a1.z;
        As[kqa * 8 + 7][ma] = a1.w;
        float4 b0 = *(const float4*)&B[(k0 + kb) * 512 + n0 + nqb * 8];
        float4 b1 = *(const float4*)&B[(k0 + kb) * 512 + n0 + nqb * 8 + 4];
        *(float4*)&Bs[kb][nqb * 8]     = b0;
        *(float4*)&Bs[kb][nqb * 8 + 4] = b1;
        __syncthreads();
#pragma unroll 16
        for (int kk = 0; kk < 64; ++kk) {
            float2 av = *(const float2*)&As[kk][tr * 2];
            float2 bv = *(const float2*)&Bs[kk][tc * 2];
            acc00 = fmaf(av.x, bv.x, acc00);
            acc01 = fmaf(av.x, bv.y, acc01);
            acc10 = fmaf(av.y, bv.x, acc10);
            acc11 = fmaf(av.y, bv.y, acc11);
        }
        __syncthreads();
    }
    float* dst = parts + blockIdx.z * 131072;
    const int m = m0 + tr * 2;
    const int nn = n0 + tc * 2;
    dst[nn * 256 + m]           = acc00;
    dst[nn * 256 + m + 1]       = acc10;
    dst[(nn + 1) * 256 + m]     = acc01;
    dst[(nn + 1) * 256 + m + 1] = acc11;
}

// ---------------------------------------------------------------------------
// Kernel 2: W2T = sum of 4 partials (blocks 0..127) and
//           b2 = lin2_w@lin1_b + lin2_b (blocks 128..135).
// ---------------------------------------------------------------------------
__global__ __launch_bounds__(256)
void w2t_fix(const float* __restrict__ parts, const float* __restrict__ lin2_w,
             const float* __restrict__ lin1_b, const float* __restrict__ lin2_b,
             float* __restrict__ W2T, float* __restrict__ b2) {
    __shared__ float red[8][33];
    const int bid = blockIdx.x;
    const int tid = threadIdx.x;
    if (bid < 128) {
        const int i = bid * 256 + tid;  // float4 index, 32768 total
        const float4* p = (const float4*)parts;
        float4 s0 = p[i];
        float4 s1 = p[i + 32768];
        float4 s2 = p[i + 65536];
        float4 s3 = p[i + 98304];
        float4 s = make_float4(s0.x + s1.x + s2.x + s3.x,
                               s0.y + s1.y + s2.y + s3.y,
                               s0.z + s1.z + s2.z + s3.z,
                               s0.w + s1.w + s2.w + s3.w);
        ((float4*)W2T)[i] = s;
    } else {
        const int np = tid & 31;
        const int ks = tid >> 5;
        const int n = (bid - 128) * 32 + np;
        float acc = 0.f;
#pragma unroll 16
        for (int k = ks * 64; k < ks * 64 + 64; k += 4) {
            float4 w  = *(const float4*)&lin2_w[n * 512 + k];
            float4 bb = *(const float4*)&lin1_b[k];
            acc += w.x * bb.x + w.y * bb.y + w.z * bb.z + w.w * bb.w;
        }
        red[ks][np] = acc;
        __syncthreads();
        if (ks == 0) {
            float s = red[0][np] + red[1][np] + red[2][np] + red[3][np] +
                      red[4][np] + red[5][np] + red[6][np] + red[7][np];
            b2[n] = s + lin2_b[n];
        }
    }
}

// ---------------------------------------------------------------------------
// Kernel 3: h[r][n2] = sum_l xt[r][l]*W2T[l*256+n2] + b2[n2]
// xt[r][l] = x[(r>>7)*65536 + l*128 + (r&127)]
// BM=BN=64, BK=32, 4x4 micro, double-buffered LDS with register prefetch:
// loads for chunk c+1 issue BEFORE compute of chunk c (per-wave latency hiding),
// one barrier per chunk.
// ---------------------------------------------------------------------------
__global__ __launch_bounds__(256)
void gemm_h(const float* __restrict__ x, const float* __restrict__ W2T,
            const float* __restrict__ b2, float* __restrict__ hout) {
    __shared__ float As[2][32][68];
    __shared__ float Bs[2][32][68];
    const int tid = threadIdx.x;
    const int bx = blockIdx.x;       // r tile of 64
    const int n0 = blockIdx.y * 64;  // n2 tile
    const int b  = bx >> 1;
    const int c0 = (bx & 1) * 64;
    const int r0 = bx * 64;
    const int cc = tid & 15;  // staging float4 col
    const int kr = tid >> 4;  // staging k row (0..15, x2)
    const int tr = tid & 15;  // r quad
    const int tc = tid >> 4;  // n quad
    float acc[4][4] = {{0.f}};

    const float* xp = x + b * 65536 + c0 + cc * 4;
    const float* wp = W2T + n0 + cc * 4;

    float4 pa0, pa1, pb0, pb1;
#define LOADC(l0)                                                              \
    do {                                                                       \
        pa0 = *(const float4*)&xp[((l0) + kr) * 128];                          \
        pa1 = *(const float4*)&xp[((l0) + kr + 16) * 128];                     \
        pb0 = *(const float4*)&wp[((l0) + kr) * 256];                          \
        pb1 = *(const float4*)&wp[((l0) + kr + 16) * 256];                     \
    } while (0)
#define STOREC(buf)                                                            \
    do {                                                                       \
        *(float4*)&As[buf][kr][cc * 4]      = pa0;                             \
        *(float4*)&As[buf][kr + 16][cc * 4] = pa1;                             \
        *(float4*)&Bs[buf][kr][cc * 4]      = pb0;                             \
        *(float4*)&Bs[buf][kr + 16][cc * 4] = pb1;                             \
    } while (0)

    LOADC(0);
    STOREC(0);
    for (int c = 0; c < 16; ++c) {
        __syncthreads();
        const int cur = c & 1;
        if (c < 15) LOADC((c + 1) * 32);
#pragma unroll
        for (int kk = 0; kk < 32; ++kk) {
            float4 av = *(const float4*)&As[cur][kk][tr * 4];
            float4 bv = *(const float4*)&Bs[cur][kk][tc * 4];
            acc[0][0] = fmaf(av.x, bv.x, acc[0][0]);
            acc[0][1] = fmaf(av.x, bv.y, acc[0][1]);
            acc[0][2] = fmaf(av.x, bv.z, acc[0][2]);
            acc[0][3] = fmaf(av.x, bv.w, acc[0][3]);
            acc[1][0] = fmaf(av.y, bv.x, acc[1][0]);
            acc[1][1] = fmaf(av.y, bv.y, acc[1][1]);
            acc[1][2] = fmaf(av.y, bv.z, acc[1][2]);
            acc[1][3] = fmaf(av.y, bv.w, acc[1][3]);
            acc[2][0] = fmaf(av.z, bv.x, acc[2][0]);
            acc[2][1] = fmaf(av.z, bv.y, acc[2][1]);
            acc[2][2] = fmaf(av.z, bv.z, acc[2][2]);
            acc[2][3] = fmaf(av.z, bv.w, acc[2][3]);
            acc[3][0] = fmaf(av.w, bv.x, acc[3][0]);
            acc[3][1] = fmaf(av.w, bv.y, acc[3][1]);
            acc[3][2] = fmaf(av.w, bv.z, acc[3][2]);
            acc[3][3] = fmaf(av.w, bv.w, acc[3][3]);
        }
        if (c < 15) STOREC(cur ^ 1);
    }
    const float4 bias = *(const float4*)&b2[n0 + tc * 4];
#pragma unroll
    for (int i = 0; i < 4; ++i) {
        float4 v = make_float4(acc[i][0] + bias.x, acc[i][1] + bias.y,
                               acc[i][2] + bias.z, acc[i][3] + bias.w);
        *(float4*)&hout[(r0 + tr * 4 + i) * 256 + n0 + tc * 4] = v;
    }
#undef LOADC
#undef STOREC
}

// ---------------------------------------------------------------------------
// Kernel 4: mamba1 over each row of h (L=256, di=2, dt_rank=1, N=16) + h.
// 4 rows per 128-thread block; 32 lanes per row: lane = (d<<4)|n.
// Phase 2 scan: 1 ds_read_b128/t + ~12 VALU + 4-stage DPP row_shr reduce.
// ---------------------------------------------------------------------------
__global__ __launch_bounds__(128)
void mamba_res(const float* __restrict__ h, float* __restrict__ out,
               const float* __restrict__ in_w, const float* __restrict__ conv_w,
               const float* __restrict__ conv_b, const float* __restrict__ xproj,
               const float* __restrict__ dt_w, const float* __restrict__ dt_b,
               const float* __restrict__ A_log, const float* __restrict__ Dp,
               const float* __restrict__ out_w) {
    __shared__ float4 arrS4[4 * 256 * 2];  // 32 KB
    __shared__ float  smem2[2048];         // 8 KB: ubuf (ph0/1) then Sbuf (ph2/3)

    const int tid = threadIdx.x;
    const int r0 = blockIdx.x * 4;
    const int row  = tid >> 5;
    const int lane = tid & 31;
    const int d    = lane >> 4;
    const int n    = lane & 15;

    // phase 0: stage 4 rows of h (coalesced)
    {
        const float4* src = (const float4*)(h + r0 * 256);
        float4* dst = (float4*)&smem2[0];
        dst[tid]       = src[tid];
        dst[tid + 128] = src[tid + 128];
    }

    const float iw0 = in_w[0], iw1 = in_w[1], iw2 = in_w[2], iw3 = in_w[3];
    const float g00 = iw0 * conv_w[0], g01 = iw0 * conv_w[1];
    const float g02 = iw0 * conv_w[2], g03 = iw0 * conv_w[3];
    const float g10 = iw1 * conv_w[4], g11 = iw1 * conv_w[5];
    const float g12 = iw1 * conv_w[6], g13 = iw1 * conv_w[7];
    const float cb0 = conv_b[0], cb1 = conv_b[1];
    const float xp00 = xproj[0], xp01 = xproj[1];
    const float dtw0 = dt_w[0], dtw1 = dt_w[1];
    const float dtb0 = dt_b[0], dtb1 = dt_b[1];
    const float D0 = Dp[0], D1 = Dp[1];
    const float ow0 = out_w[0], ow1 = out_w[1];

    __syncthreads();

    // phase 1: per-t precompute; keep w0/w1/base in registers for phase 3
    float w0a[8], w1a[8], basea[8];
#pragma unroll
    for (int j = 0; j < 8; ++j) {
        const int t = lane + 32 * j;
        const float* u = &smem2[row * 256];
        const float u0 = u[t];
        const int i1 = (t >= 1) ? t - 1 : 0;
        const int i2 = (t >= 2) ? t - 2 : 0;
        const int i3 = (t >= 3) ? t - 3 : 0;
        float um1 = u[i1]; um1 = (t >= 1) ? um1 : 0.f;
        float um2 = u[i2]; um2 = (t >= 2) ? um2 : 0.f;
        float um3 = u[i3]; um3 = (t >= 3) ? um3 : 0.f;

        const float p0 = fmaf(g03, u0, fmaf(g02, um1, fmaf(g01, um2, fmaf(g00, um3, cb0))));
        const float p1 = fmaf(g13, u0, fmaf(g12, um1, fmaf(g11, um2, fmaf(g10, um3, cb1))));
        const float xc0 = silu_f(p0);
        const float xc1 = silu_f(p1);
        const float dbc0 = fmaf(xp01, xc1, xp00 * xc0);
        const float dt0 = softplus_f(fmaf(dbc0, dtw0, dtb0));
        const float dt1 = softplus_f(fmaf(dbc0, dtw1, dtb1));
        const float e0 = dt0 * xc0;
        const float e1 = dt1 * xc1;
        const float w0 = silu_f(u0 * iw2) * ow0;
        const float w1 = silu_f(u0 * iw3) * ow1;
        w0a[j] = w0;
        w1a[j] = w1;
        basea[j] = fmaf(xc1 * D1, w1, fmaf(xc0 * D0, w0, u0));
        const int base_idx = (row * 256 + t) * 2;
        arrS4[base_idx]     = make_float4(xc0, xc1, dt0, e0);
        arrS4[base_idx + 1] = make_float4(xc0, xc1, dt1, e1);
    }
    __syncthreads();  // arrS ready; smem2 free to be reused as Sbuf

    // phase 2: sequential scan; lane owns state (d, n)
    const float a_dn = -__expf(A_log[d * 16 + n]);
    const float bn0 = xproj[(1 + n) * 2 + 0];
    const float bn1 = xproj[(1 + n) * 2 + 1];
    const float cn0 = xproj[(17 + n) * 2 + 0];
    const float cn1 = xproj[(17 + n) * 2 + 1];
    const bool is_writer = ((lane & 15) == 15);
    float hstate = 0.f;

#pragma unroll 4
    for (int t = 0; t < 256; ++t) {
        const float4 P = arrS4[((row * 256 + t) << 1) + d];  // {xc0,xc1,dt_d,e_d}
        const float bm = fmaf(bn0, P.x, bn1 * P.y);
        const float cm = fmaf(cn0, P.x, cn1 * P.y);
        const float dA = __expf(P.z * a_dn);
        hstate = fmaf(dA, hstate, P.w * bm);
        float s = hstate * cm;
        DPP_ADD(s, 0x111);  // row_shr:1
        DPP_ADD(s, 0x112);  // row_shr:2
        DPP_ADD(s, 0x114);  // row_shr:4
        DPP_ADD(s, 0x118);  // row_shr:8 -> lane15 of each 16-row has S_d
        if (is_writer) smem2[((row * 256 + t) << 1) + d] = s;
    }
    __syncthreads();

    // phase 3: y = base + w0*S0 + w1*S1, coalesced stores
    float* orow = out + (r0 + row) * 256;
#pragma unroll
    for (int j = 0; j < 8; ++j) {
        const int t = lane + 32 * j;
        const float2 S = *(const float2*)&smem2[((row * 256 + t) << 1)];
        orow[t] = fmaf(w1a[j], S.y, fmaf(w0a[j], S.x, basea[j]));
    }
}

// ---------------------------------------------------------------------------
extern "C" void kernel_launch(void* const* d_in, const int* in_sizes, int n_in,
                              void* d_out, int out_size, void* d_ws, size_t ws_size,
                              hipStream_t stream) {
    const float* x      = (const float*)d_in[0];
    const float* lin1_w = (const float*)d_in[1];
    const float* lin1_b = (const float*)d_in[2];
    const float* lin2_w = (const float*)d_in[3];
    const float* lin2_b = (const float*)d_in[4];
    const float* m1_in_w   = (const float*)d_in[5];
    const float* m1_conv_w = (const float*)d_in[6];
    const float* m1_conv_b = (const float*)d_in[7];
    const float* m1_xproj  = (const float*)d_in[8];
    const float* m1_dt_w   = (const float*)d_in[9];
    const float* m1_dt_b   = (const float*)d_in[10];
    const float* m1_A_log  = (const float*)d_in[11];
    const float* m1_D      = (const float*)d_in[12];
    const float* m1_out_w  = (const float*)d_in[13];
    // d_in[14..22] = m2_* params: x1 branch is exactly zero (see analysis)

    float* out  = (float*)d_out;
    float* wsf  = (float*)d_ws;
    float* W2T   = wsf;                  // 131072 floats
    float* b2    = wsf + 131072;         // 256 (+pad)
    float* parts = wsf + 131328;         // 524288 floats (dead after w2t_fix)
    float* hbuf  = wsf + 131328;         // 1048576 floats (aliases parts)

    gemm_w2t_part<<<dim3(8, 16, 4), 256, 0, stream>>>(lin2_w, lin1_w, parts);
    w2t_fix<<<136, 256, 0, stream>>>(parts, lin2_w, lin1_b, lin2_b, W2T, b2);
    gemm_h<<<dim3(64, 4), 256, 0, stream>>>(x, W2T, b2, hbuf);
    mamba_res<<<1024, 128, 0, stream>>>(hbuf, out, m1_in_w, m1_conv_w, m1_conv_b,
                                        m1_xproj, m1_dt_w, m1_dt_b, m1_A_log,
                                        m1_D, m1_out_w);
}